// Round 9
// baseline (2297.482 us; speedup 1.0000x reference)
//
#include <hip/hip_runtime.h>
#include <math.h>

#define B_N 4096
#define E_N 512
#define C_N 8
#define NU 64
#define BK 16
#define NDEPTH 8
#define MROWS 1536   // NU*BK + E_N
#define THR 0.001f
#define EPSV 1e-8f
#define NTOT (B_N * C_N)   // 32768 score columns
#define WSCALE 64.0f       // lifts W entries (~0.04) out of fp16-subnormal range
#define RSCALE 32.0f       // fixed residual scale (rho = RSCALE*r); cancels in
                           // scores, coeffs/proj run in rho-space, out=x-rho/32
#define RINV (1.0f / 32.0f)
#define CH 256             // e-chunk for update staging
#define RSP 264            // rsc row stride (floats) for the 256-wide CHUNK tile
#define FSP 520            // row stride (floats) for FULL-E (512) transpose tiles
                           // (round-8 bug: used RSP=264 here -> LDS row overflow)
#define BSP 17             // padded basis stride (bank-conflict-free)

typedef _Float16 f16;
typedef f16 f16x8 __attribute__((ext_vector_type(8)));
typedef float f32x4 __attribute__((ext_vector_type(4)));

// ---------------- build W (fp16 hi/lo, scaled): W[m][e], m in [0,1536) ------
__global__ void build_w(const float* __restrict__ basis,
                        const float* __restrict__ hasher,
                        f16* __restrict__ whi, f16* __restrict__ wlo) {
  const int m = blockIdx.x;
  const int t = threadIdx.x;
  float a0, a1;
  if (m < NU * BK) {
    const int n = m >> 4, k = m & 15;
    const float* bp = basis + (size_t)n * E_N * BK + k;
    a0 = 0.f; a1 = 0.f;
    for (int e = 0; e < E_N; ++e) {
      const float bv = bp[(size_t)e * BK];
      const float* hrow = hasher + (size_t)e * E_N;
      a0 = fmaf(bv, hrow[t], a0);
      a1 = fmaf(bv, hrow[t + 256], a1);
    }
  } else {
    const int e = m - NU * BK;
    a0 = hasher[(size_t)e * E_N + t];
    a1 = hasher[(size_t)e * E_N + t + 256];
  }
  a0 *= WSCALE; a1 *= WSCALE;
  const f16 h0 = (f16)a0, h1 = (f16)a1;
  whi[(size_t)m * E_N + t] = h0;
  wlo[(size_t)m * E_N + t] = (f16)(a0 - (float)h0);
  whi[(size_t)m * E_N + t + 256] = h1;
  wlo[(size_t)m * E_N + t + 256] = (f16)(a1 - (float)h1);
}

// ---------------- init: x -> rT hi/lo (scaled, transposed) ------------------
__launch_bounds__(256)
__global__ void init_convert(const float* __restrict__ x,
                             f16* __restrict__ rThi, f16* __restrict__ rTlo) {
  __shared__ float TT[C_N * FSP];
  const int tid = threadIdx.x;
  const int b = blockIdx.x;
  const float* xb = x + (size_t)b * E_N * C_N;
  for (int i = tid; i < E_N * C_N / 4; i += 256) {
    const float4 v = ((const float4*)xb)[i];
    const int e = i >> 1, c4 = (i & 1) * 4;
    TT[(c4 + 0) * FSP + e] = v.x;
    TT[(c4 + 1) * FSP + e] = v.y;
    TT[(c4 + 2) * FSP + e] = v.z;
    TT[(c4 + 3) * FSP + e] = v.w;
  }
  __syncthreads();
  const int c = tid >> 5, seg = tid & 31;
  const size_t row = ((size_t)b * C_N + c) * E_N;
#pragma unroll
  for (int hf = 0; hf < 2; ++hf) {
    const int e0 = seg * 16 + hf * 8;
    f16x8 oh, ol;
#pragma unroll
    for (int j = 0; j < 8; ++j) {
      const float v = TT[c * FSP + e0 + j] * RSCALE;
      const f16 h = (f16)v;
      oh[j] = h; ol[j] = (f16)(v - (float)h);
    }
    *(f16x8*)&rThi[row + e0] = oh;
    *(f16x8*)&rTlo[row + e0] = ol;
  }
}

// ---------------- MFMA score kernel (full N, one dispatch per depth) --------
// z = W*rT^T via 3-term fp16 split: Whi*rhi + Whi*rlo + Wlo*rhi (fp32 acc).
// 128x128 tile, 4 waves, BK=32, 16 K-steps. Grid 3072 = 12 Mt x 256 Nt.
__launch_bounds__(256, 2)
__global__ void mfma_score(const f16* __restrict__ whi, const f16* __restrict__ wlo,
                           const f16* __restrict__ rThi, const f16* __restrict__ rTlo,
                           float* __restrict__ part, float* __restrict__ nupart) {
  __shared__ f16 Ah[128 * 32], Al[128 * 32], Bh[128 * 32], Bl[128 * 32];
  __shared__ float nred[2][128];
  const int tid = threadIdx.x;
  const int lane = tid & 63;
  const int w = tid >> 6, wm = w >> 1, wn = w & 1;
  // XCD-aware swizzle: 3072 blocks = 8 XCDs x 384 (= 32 N-panels x 12 M-tiles)
  const int bid = blockIdx.x;
  const int nid = (bid & 7) * 384 + (bid >> 3);
  const int mt = nid % 12, nt = nid / 12;
  const int m0 = mt * 128;
  const int nq0 = nt * 128;
  const int l15 = lane & 15, lk = lane >> 4;

  const f32x4 fz = {0.f, 0.f, 0.f, 0.f};
  f32x4 acc[4][4];
#pragma unroll
  for (int i = 0; i < 4; ++i)
#pragma unroll
    for (int j = 0; j < 4; ++j) acc[i][j] = fz;

  const int h0 = tid, h1 = 256 + tid;
  const int r0 = h0 >> 2, c0 = h0 & 3, r1 = h1 >> 2, c1 = h1 & 3;
  const int s0 = (h0 & ~3) | (c0 ^ (r0 & 3));   // XOR chunk swizzle
  const int s1 = (h1 & ~3) | (c1 ^ (r1 & 3));
  const size_t aoff0 = (size_t)(m0 + r0) * E_N + c0 * 8;
  const size_t aoff1 = (size_t)(m0 + r1) * E_N + c1 * 8;
  const size_t boff0 = (size_t)(nq0 + r0) * E_N + c0 * 8;
  const size_t boff1 = (size_t)(nq0 + r1) * E_N + c1 * 8;

  f16x8 vah0 = *(const f16x8*)(whi + aoff0);
  f16x8 vah1 = *(const f16x8*)(whi + aoff1);
  f16x8 val0 = *(const f16x8*)(wlo + aoff0);
  f16x8 val1 = *(const f16x8*)(wlo + aoff1);
  f16x8 vbh0 = *(const f16x8*)(rThi + boff0);
  f16x8 vbh1 = *(const f16x8*)(rThi + boff1);
  f16x8 vbl0 = *(const f16x8*)(rTlo + boff0);
  f16x8 vbl1 = *(const f16x8*)(rTlo + boff1);

  for (int ks = 0; ks < 16; ++ks) {
    __syncthreads();
    ((f16x8*)Ah)[s0] = vah0; ((f16x8*)Ah)[s1] = vah1;
    ((f16x8*)Al)[s0] = val0; ((f16x8*)Al)[s1] = val1;
    ((f16x8*)Bh)[s0] = vbh0; ((f16x8*)Bh)[s1] = vbh1;
    ((f16x8*)Bl)[s0] = vbl0; ((f16x8*)Bl)[s1] = vbl1;
    __syncthreads();
    if (ks < 15) {
      const size_t ko = (size_t)(ks + 1) * 32;
      vah0 = *(const f16x8*)(whi + aoff0 + ko);
      vah1 = *(const f16x8*)(whi + aoff1 + ko);
      val0 = *(const f16x8*)(wlo + aoff0 + ko);
      val1 = *(const f16x8*)(wlo + aoff1 + ko);
      vbh0 = *(const f16x8*)(rThi + boff0 + ko);
      vbh1 = *(const f16x8*)(rThi + boff1 + ko);
      vbl0 = *(const f16x8*)(rTlo + boff0 + ko);
      vbl1 = *(const f16x8*)(rTlo + boff1 + ko);
    }
    f16x8 bhf[4], blf[4];
#pragma unroll
    for (int fn = 0; fn < 4; ++fn) {
      const int row = wn * 64 + fn * 16 + l15;
      const int idx = row * 4 + (lk ^ (row & 3));
      bhf[fn] = ((const f16x8*)Bh)[idx];
      blf[fn] = ((const f16x8*)Bl)[idx];
    }
#pragma unroll
    for (int fm = 0; fm < 4; ++fm) {
      const int row = wm * 64 + fm * 16 + l15;
      const int idx = row * 4 + (lk ^ (row & 3));
      const f16x8 ahf = ((const f16x8*)Ah)[idx];
      const f16x8 alf = ((const f16x8*)Al)[idx];
#pragma unroll
      for (int fn = 0; fn < 4; ++fn) {
        acc[fm][fn] = __builtin_amdgcn_mfma_f32_16x16x32_f16(ahf, bhf[fn], acc[fm][fn], 0, 0, 0);
        acc[fm][fn] = __builtin_amdgcn_mfma_f32_16x16x32_f16(ahf, blf[fn], acc[fm][fn], 0, 0, 0);
        acc[fm][fn] = __builtin_amdgcn_mfma_f32_16x16x32_f16(alf, bhf[fn], acc[fm][fn], 0, 0, 0);
      }
    }
  }

  // epilogue: C/D frag layout col = lane&15, row = (lane>>4)*4 + reg
  if (m0 < NU * BK) {
#pragma unroll
    for (int fm = 0; fm < 4; ++fm) {
      const int u = (m0 >> 4) + wm * 4 + fm;
#pragma unroll
      for (int fn = 0; fn < 4; ++fn) {
        const f32x4 a = acc[fm][fn];
        float s = a.x * a.x + a.y * a.y + a.z * a.z + a.w * a.w;
        s += __shfl_xor(s, 16);
        s += __shfl_xor(s, 32);   // 16-row (one unit) column sum
        if (lk == 0)
          part[(size_t)u * NTOT + nq0 + wn * 64 + fn * 16 + l15] = s;
      }
    }
  } else {
#pragma unroll
    for (int fn = 0; fn < 4; ++fn) {
      float s = 0.f;
#pragma unroll
      for (int fm = 0; fm < 4; ++fm) {
        const f32x4 a = acc[fm][fn];
        s += a.x * a.x + a.y * a.y + a.z * a.z + a.w * a.w;
      }
      s += __shfl_xor(s, 16);
      s += __shfl_xor(s, 32);
      if (lk == 0) nred[wm][wn * 64 + fn * 16 + l15] = s;
    }
    __syncthreads();
    if (tid < 128)
      nupart[(size_t)((m0 - NU * BK) >> 7) * NTOT + nq0 + tid] =
          nred[0][tid] + nred[1][tid];
  }
}

// ---------------- update: score+argmax+coeffs+proj, rT hi/lo in-place -------
// e-chunked staging (2 x 256) keeps LDS ~30 KB -> 5 blocks/CU.
__launch_bounds__(256, 4)
__global__ void update2(const float* __restrict__ basis,
                        f16* __restrict__ rThi, f16* __restrict__ rTlo,
                        const float* __restrict__ part,
                        const float* __restrict__ nupart,
                        unsigned char* __restrict__ used,
                        float* __restrict__ init_energy,
                        const int depth) {
  __shared__ float bshc[CH * BSP];   // 17.4 KB  basis chunk [e_local][k], pad 17
  __shared__ float rsc[C_N * RSP];   // 8.4 KB   rho chunk   [c][e_local]
  __shared__ float prt[4][BK * C_N];
  __shared__ float coeffs[BK * C_N];
  __shared__ float epart[256];
  __shared__ float sval[NU];
  __shared__ float scale_sh[C_N];
  __shared__ int sbu;
  const int b = blockIdx.x;
  const int tid = threadIdx.x;
  const int c = tid >> 5, seg = tid & 31;
  const size_t row = ((size_t)b * C_N + c) * E_N;

  if (tid < C_N) {
    float nu = 0.f;
#pragma unroll
    for (int t4 = 0; t4 < 4; ++t4)
      nu += nupart[(size_t)t4 * NTOT + b * C_N + tid];
    const float inv = 1.f / (sqrtf(nu) + EPSV);
    scale_sh[tid] = inv * inv;
  }
  __syncthreads();
  if (tid < NU) {   // score[u]; masked by used (scores >= 0 -> -1 sentinel)
    const float* pu = part + (size_t)tid * NTOT + b * C_N;
    float s = 0.f;
#pragma unroll
    for (int cc = 0; cc < C_N; ++cc) s = fmaf(pu[cc], scale_sh[cc], s);
    if (used[(size_t)b * NU + tid]) s = -1.f;
    sval[tid] = s;
  }
  // load chunk0 -> rsc, energy part
  float en = 0.f;
  {
    const f16x8 h = *(const f16x8*)&rThi[row + seg * 8];
    const f16x8 l = *(const f16x8*)&rTlo[row + seg * 8];
    float4 v0, v1;
    float* vv0 = (float*)&v0; float* vv1 = (float*)&v1;
#pragma unroll
    for (int j = 0; j < 4; ++j) {
      const float v = (float)h[j] + (float)l[j];
      vv0[j] = v; en = fmaf(v, v, en);
    }
#pragma unroll
    for (int j = 0; j < 4; ++j) {
      const float v = (float)h[4 + j] + (float)l[4 + j];
      vv1[j] = v; en = fmaf(v, v, en);
    }
    *(float4*)&rsc[c * RSP + seg * 8] = v0;
    *(float4*)&rsc[c * RSP + seg * 8 + 4] = v1;
  }
  __syncthreads();                 // sval + rsc chunk0 ready
  if (tid == 255) {                // first-max-wins argmax (jnp.argmax)
    float bs = -2.f; int bi = 0;
    for (int u = 0; u < NU; ++u)
      if (sval[u] > bs) { bs = sval[u]; bi = u; }
    sbu = bi;
  }
  __syncthreads();
  const int bu = sbu;
  const float* bp = basis + (size_t)bu * E_N * BK;
  for (int i = tid; i < CH * BK / 4; i += 256) {   // stage basis chunk0
    const float4 wv = ((const float4*)bp)[i];
    const int f0 = i * 4, e = f0 >> 4, k = f0 & 15;
    bshc[e * BSP + k] = wv.x;     bshc[e * BSP + k + 1] = wv.y;
    bshc[e * BSP + k + 2] = wv.z; bshc[e * BSP + k + 3] = wv.w;
  }
  __syncthreads();
  {  // coeffs partials chunk0: (k, c2, half) = 16 x 8 x 2
    const int k = tid >> 4, c2 = (tid >> 1) & 7, hh = tid & 1;
    float s = 0.f;
    const int e0 = hh * 128;
    for (int e = e0; e < e0 + 128; ++e)
      s = fmaf(bshc[e * BSP + k], rsc[c2 * RSP + e], s);
    prt[hh][k * C_N + c2] = s;
  }
  __syncthreads();                 // chunk0 consumed
  {  // load chunk1 -> rsc, energy part
    const f16x8 h = *(const f16x8*)&rThi[row + CH + seg * 8];
    const f16x8 l = *(const f16x8*)&rTlo[row + CH + seg * 8];
    float4 v0, v1;
    float* vv0 = (float*)&v0; float* vv1 = (float*)&v1;
#pragma unroll
    for (int j = 0; j < 4; ++j) {
      const float v = (float)h[j] + (float)l[j];
      vv0[j] = v; en = fmaf(v, v, en);
    }
#pragma unroll
    for (int j = 0; j < 4; ++j) {
      const float v = (float)h[4 + j] + (float)l[4 + j];
      vv1[j] = v; en = fmaf(v, v, en);
    }
    *(float4*)&rsc[c * RSP + seg * 8] = v0;
    *(float4*)&rsc[c * RSP + seg * 8 + 4] = v1;
  }
  for (int i = tid; i < CH * BK / 4; i += 256) {   // stage basis chunk1
    const float4 wv = ((const float4*)bp)[CH * BK / 4 + i];
    const int f0 = i * 4, e = f0 >> 4, k = f0 & 15;   // e local to chunk1
    bshc[e * BSP + k] = wv.x;     bshc[e * BSP + k + 1] = wv.y;
    bshc[e * BSP + k + 2] = wv.z; bshc[e * BSP + k + 3] = wv.w;
  }
  epart[tid] = en;
  __syncthreads();
  {  // coeffs partials chunk1
    const int k = tid >> 4, c2 = (tid >> 1) & 7, hh = tid & 1;
    float s = 0.f;
    const int e0 = hh * 128;
    for (int e = e0; e < e0 + 128; ++e)
      s = fmaf(bshc[e * BSP + k], rsc[c2 * RSP + e], s);
    prt[2 + hh][k * C_N + c2] = s;
  }
  __syncthreads();
  if (tid < 128)
    coeffs[tid] = (prt[0][tid] + prt[1][tid]) + (prt[2][tid] + prt[3][tid]);
  for (int s = 128; s > 0; s >>= 1) {   // deterministic energy tree
    if (tid < s) epart[tid] += epart[tid + s];
    __syncthreads();
  }
  const float etot = epart[0];
  float ie;
  if (depth == 0) {
    ie = etot;
    if (tid == 0) init_energy[b] = etot;
  } else {
    ie = init_energy[b];
  }
  const bool act = etot > THR * ie;   // block-uniform
  if (act) {
    // proj chunk1 (rsc/bshc currently hold chunk1), direct coalesced f16 store
    {
      f16x8 oh, ol;
#pragma unroll
      for (int j = 0; j < 8; ++j) {
        const int e = seg * 8 + j;
        float pv = 0.f;
#pragma unroll
        for (int k = 0; k < BK; ++k)
          pv = fmaf(bshc[e * BSP + k], coeffs[k * C_N + c], pv);
        const float rv = rsc[c * RSP + e] - pv;
        const f16 h = (f16)rv;
        oh[j] = h; ol[j] = (f16)(rv - (float)h);
      }
      *(f16x8*)&rThi[row + CH + seg * 8] = oh;
      *(f16x8*)&rTlo[row + CH + seg * 8] = ol;
    }
    __syncthreads();
    // restage chunk0 (rT re-read is L2-hot) and proj chunk0
    {
      const f16x8 h = *(const f16x8*)&rThi[row + seg * 8];
      const f16x8 l = *(const f16x8*)&rTlo[row + seg * 8];
#pragma unroll
      for (int j = 0; j < 8; ++j)
        rsc[c * RSP + seg * 8 + j] = (float)h[j] + (float)l[j];
    }
    for (int i = tid; i < CH * BK / 4; i += 256) {
      const float4 wv = ((const float4*)bp)[i];
      const int f0 = i * 4, e = f0 >> 4, k = f0 & 15;
      bshc[e * BSP + k] = wv.x;     bshc[e * BSP + k + 1] = wv.y;
      bshc[e * BSP + k + 2] = wv.z; bshc[e * BSP + k + 3] = wv.w;
    }
    __syncthreads();
    {
      f16x8 oh, ol;
#pragma unroll
      for (int j = 0; j < 8; ++j) {
        const int e = seg * 8 + j;
        float pv = 0.f;
#pragma unroll
        for (int k = 0; k < BK; ++k)
          pv = fmaf(bshc[e * BSP + k], coeffs[k * C_N + c], pv);
        const float rv = rsc[c * RSP + e] - pv;
        const f16 h = (f16)rv;
        oh[j] = h; ol[j] = (f16)(rv - (float)h);
      }
      *(f16x8*)&rThi[row + seg * 8] = oh;
      *(f16x8*)&rTlo[row + seg * 8] = ol;
    }
    if (tid == 0) used[(size_t)b * NU + bu] = 1;
  }
}

// ---------------- finalize: out[b][e][c] = x - (hi+lo)*RINV -----------------
__launch_bounds__(256)
__global__ void finalize2(const float* __restrict__ x,
                          const f16* __restrict__ rThi,
                          const f16* __restrict__ rTlo,
                          float* __restrict__ out) {
  __shared__ float TT[C_N * FSP];
  const int tid = threadIdx.x;
  const int b = blockIdx.x;
  const int c = tid >> 5, seg = tid & 31;
  const size_t row = ((size_t)b * C_N + c) * E_N;
#pragma unroll
  for (int hf = 0; hf < 2; ++hf) {
    const int e0 = seg * 16 + hf * 8;
    const f16x8 h = *(const f16x8*)&rThi[row + e0];
    const f16x8 l = *(const f16x8*)&rTlo[row + e0];
#pragma unroll
    for (int j = 0; j < 8; ++j)
      TT[c * FSP + e0 + j] = (float)h[j] + (float)l[j];
  }
  __syncthreads();
  const float* xb = x + (size_t)b * E_N * C_N;
  float* ob = out + (size_t)b * E_N * C_N;
  for (int i = tid; i < E_N * C_N / 4; i += 256) {
    const float4 xv = ((const float4*)xb)[i];
    const int e = i >> 1, c4 = (i & 1) * 4;
    float4 o;
    o.x = xv.x - TT[(c4 + 0) * FSP + e] * RINV;
    o.y = xv.y - TT[(c4 + 1) * FSP + e] * RINV;
    o.z = xv.z - TT[(c4 + 2) * FSP + e] * RINV;
    o.w = xv.w - TT[(c4 + 3) * FSP + e] * RINV;
    ((float4*)ob)[i] = o;
  }
}

extern "C" void kernel_launch(void* const* d_in, const int* in_sizes, int n_in,
                              void* d_out, int out_size, void* d_ws, size_t ws_size,
                              hipStream_t stream) {
  const float* x      = (const float*)d_in[0];
  const float* basis  = (const float*)d_in[1];
  const float* hasher = (const float*)d_in[2];
  float* out = (float*)d_out;

  // workspace layout (~75.8 MB)
  float* part        = (float*)d_ws;                         // 8 MB
  float* nupart      = part + (size_t)NU * NTOT;             // 512 KB
  float* init_energy = nupart + (size_t)4 * NTOT;            // 16 KB
  f16*   whi         = (f16*)(init_energy + B_N);            // 1.5 MB
  f16*   wlo         = whi + (size_t)MROWS * E_N;            // 1.5 MB
  f16*   rThi        = wlo + (size_t)MROWS * E_N;            // 32 MB
  f16*   rTlo        = rThi + (size_t)NTOT * E_N;            // 32 MB
  unsigned char* used = (unsigned char*)(rTlo + (size_t)NTOT * E_N); // 256 KB

  hipMemsetAsync(used, 0, (size_t)B_N * NU, stream);
  build_w<<<MROWS, 256, 0, stream>>>(basis, hasher, whi, wlo);
  init_convert<<<B_N, 256, 0, stream>>>(x, rThi, rTlo);

  for (int d = 0; d < NDEPTH; ++d) {
    mfma_score<<<3072, 256, 0, stream>>>(whi, wlo, rThi, rTlo, part, nupart);
    update2<<<B_N, 256, 0, stream>>>(basis, rThi, rTlo, part, nupart, used,
                                     init_energy, d);
  }
  finalize2<<<B_N, 256, 0, stream>>>(x, rThi, rTlo, out);
}

// Round 10
// 2284.334 us; speedup vs baseline: 1.0058x; 1.0058x over previous
//
#include <hip/hip_runtime.h>
#include <math.h>

#define B_N 4096
#define E_N 512
#define C_N 8
#define NU 64
#define BK 16
#define NDEPTH 8
#define MROWS 1536   // NU*BK + E_N
#define THR 0.001f
#define EPSV 1e-8f
#define NTOT (B_N * C_N)   // 32768 score columns
#define WSCALE 64.0f       // lifts W entries (~0.04) out of fp16-subnormal range
#define RSCALE 32.0f       // fixed residual scale (rho = RSCALE*r); cancels in
                           // scores, coeffs/proj run in rho-space, out=x-rho/32
#define RINV (1.0f / 32.0f)
#define CH 256             // e-chunk for update staging
#define RSP 264            // rsc row stride (floats) for the 256-wide CHUNK tile
#define FSP 520            // row stride (floats) for FULL-E (512) transpose tiles
#define BSP 17             // padded basis stride (bank-conflict-free)

typedef _Float16 f16;
typedef f16 f16x8 __attribute__((ext_vector_type(8)));
typedef float f32x4 __attribute__((ext_vector_type(4)));

// ---------------- build W (fp16 hi/lo, scaled): W[m][e], m in [0,1536) ------
__global__ void build_w(const float* __restrict__ basis,
                        const float* __restrict__ hasher,
                        f16* __restrict__ whi, f16* __restrict__ wlo) {
  const int m = blockIdx.x;
  const int t = threadIdx.x;
  float a0, a1;
  if (m < NU * BK) {
    const int n = m >> 4, k = m & 15;
    const float* bp = basis + (size_t)n * E_N * BK + k;
    a0 = 0.f; a1 = 0.f;
    for (int e = 0; e < E_N; ++e) {
      const float bv = bp[(size_t)e * BK];
      const float* hrow = hasher + (size_t)e * E_N;
      a0 = fmaf(bv, hrow[t], a0);
      a1 = fmaf(bv, hrow[t + 256], a1);
    }
  } else {
    const int e = m - NU * BK;
    a0 = hasher[(size_t)e * E_N + t];
    a1 = hasher[(size_t)e * E_N + t + 256];
  }
  a0 *= WSCALE; a1 *= WSCALE;
  const f16 h0 = (f16)a0, h1 = (f16)a1;
  whi[(size_t)m * E_N + t] = h0;
  wlo[(size_t)m * E_N + t] = (f16)(a0 - (float)h0);
  whi[(size_t)m * E_N + t + 256] = h1;
  wlo[(size_t)m * E_N + t + 256] = (f16)(a1 - (float)h1);
}

// ---------------- init: x -> rT hi/lo (scaled, transposed) ------------------
__launch_bounds__(256)
__global__ void init_convert(const float* __restrict__ x,
                             f16* __restrict__ rThi, f16* __restrict__ rTlo) {
  __shared__ float TT[C_N * FSP];
  const int tid = threadIdx.x;
  const int b = blockIdx.x;
  const float* xb = x + (size_t)b * E_N * C_N;
  for (int i = tid; i < E_N * C_N / 4; i += 256) {
    const float4 v = ((const float4*)xb)[i];
    const int e = i >> 1, c4 = (i & 1) * 4;
    TT[(c4 + 0) * FSP + e] = v.x;
    TT[(c4 + 1) * FSP + e] = v.y;
    TT[(c4 + 2) * FSP + e] = v.z;
    TT[(c4 + 3) * FSP + e] = v.w;
  }
  __syncthreads();
  const int c = tid >> 5, seg = tid & 31;
  const size_t row = ((size_t)b * C_N + c) * E_N;
#pragma unroll
  for (int hf = 0; hf < 2; ++hf) {
    const int e0 = seg * 16 + hf * 8;
    f16x8 oh, ol;
#pragma unroll
    for (int j = 0; j < 8; ++j) {
      const float v = TT[c * FSP + e0 + j] * RSCALE;
      const f16 h = (f16)v;
      oh[j] = h; ol[j] = (f16)(v - (float)h);
    }
    *(f16x8*)&rThi[row + e0] = oh;
    *(f16x8*)&rTlo[row + e0] = ol;
  }
}

// ---------------- MFMA score kernel (full N, one dispatch per depth) --------
// z = W*rT^T via 3-term fp16 split: Whi*rhi + Whi*rlo + Wlo*rhi (fp32 acc).
// 128x128 tile, 4 waves, BK=32, 16 K-steps. Grid 3072 = 12 Mt x 256 Nt.
// LDS chunk swizzle: chunk' = chunk ^ (row&3) ^ ((row>>2)&3) -- balanced
// 2 lanes per 16B bank-slot in every 16-lane quarter (round-9's lk^(row&3)
// left 4-way read conflicts: 1.26e7 SQ_LDS_BANK_CONFLICT/dispatch).
__launch_bounds__(256, 2)
__global__ void mfma_score(const f16* __restrict__ whi, const f16* __restrict__ wlo,
                           const f16* __restrict__ rThi, const f16* __restrict__ rTlo,
                           float* __restrict__ part, float* __restrict__ nupart) {
  __shared__ f16 Ah[128 * 32], Al[128 * 32], Bh[128 * 32], Bl[128 * 32];
  __shared__ float nred[2][128];
  const int tid = threadIdx.x;
  const int lane = tid & 63;
  const int w = tid >> 6, wm = w >> 1, wn = w & 1;
  // XCD-aware swizzle: 3072 blocks = 8 XCDs x 384 (= 32 N-panels x 12 M-tiles)
  const int bid = blockIdx.x;
  const int nid = (bid & 7) * 384 + (bid >> 3);
  const int mt = nid % 12, nt = nid / 12;
  const int m0 = mt * 128;
  const int nq0 = nt * 128;
  const int l15 = lane & 15, lk = lane >> 4;
  // loop-invariant read swizzle: row = 16*a + l15 -> (row&3)^((row>>2)&3)
  //                                                = (l15&3)^((l15>>2)&3)
  const int rsw = lk ^ (l15 & 3) ^ ((l15 >> 2) & 3);

  const f32x4 fz = {0.f, 0.f, 0.f, 0.f};
  f32x4 acc[4][4];
#pragma unroll
  for (int i = 0; i < 4; ++i)
#pragma unroll
    for (int j = 0; j < 4; ++j) acc[i][j] = fz;

  const int h0 = tid, h1 = 256 + tid;
  const int r0 = h0 >> 2, c0 = h0 & 3, r1 = h1 >> 2, c1 = h1 & 3;
  const int s0 = (h0 & ~3) | (c0 ^ (r0 & 3) ^ ((r0 >> 2) & 3));
  const int s1 = (h1 & ~3) | (c1 ^ (r1 & 3) ^ ((r1 >> 2) & 3));
  const size_t aoff0 = (size_t)(m0 + r0) * E_N + c0 * 8;
  const size_t aoff1 = (size_t)(m0 + r1) * E_N + c1 * 8;
  const size_t boff0 = (size_t)(nq0 + r0) * E_N + c0 * 8;
  const size_t boff1 = (size_t)(nq0 + r1) * E_N + c1 * 8;

  f16x8 vah0 = *(const f16x8*)(whi + aoff0);
  f16x8 vah1 = *(const f16x8*)(whi + aoff1);
  f16x8 val0 = *(const f16x8*)(wlo + aoff0);
  f16x8 val1 = *(const f16x8*)(wlo + aoff1);
  f16x8 vbh0 = *(const f16x8*)(rThi + boff0);
  f16x8 vbh1 = *(const f16x8*)(rThi + boff1);
  f16x8 vbl0 = *(const f16x8*)(rTlo + boff0);
  f16x8 vbl1 = *(const f16x8*)(rTlo + boff1);

  for (int ks = 0; ks < 16; ++ks) {
    __syncthreads();
    ((f16x8*)Ah)[s0] = vah0; ((f16x8*)Ah)[s1] = vah1;
    ((f16x8*)Al)[s0] = val0; ((f16x8*)Al)[s1] = val1;
    ((f16x8*)Bh)[s0] = vbh0; ((f16x8*)Bh)[s1] = vbh1;
    ((f16x8*)Bl)[s0] = vbl0; ((f16x8*)Bl)[s1] = vbl1;
    __syncthreads();
    if (ks < 15) {
      const size_t ko = (size_t)(ks + 1) * 32;
      vah0 = *(const f16x8*)(whi + aoff0 + ko);
      vah1 = *(const f16x8*)(whi + aoff1 + ko);
      val0 = *(const f16x8*)(wlo + aoff0 + ko);
      val1 = *(const f16x8*)(wlo + aoff1 + ko);
      vbh0 = *(const f16x8*)(rThi + boff0 + ko);
      vbh1 = *(const f16x8*)(rThi + boff1 + ko);
      vbl0 = *(const f16x8*)(rTlo + boff0 + ko);
      vbl1 = *(const f16x8*)(rTlo + boff1 + ko);
    }
    f16x8 bhf[4], blf[4];
#pragma unroll
    for (int fn = 0; fn < 4; ++fn) {
      const int row = wn * 64 + fn * 16 + l15;
      const int idx = row * 4 + rsw;
      bhf[fn] = ((const f16x8*)Bh)[idx];
      blf[fn] = ((const f16x8*)Bl)[idx];
    }
#pragma unroll
    for (int fm = 0; fm < 4; ++fm) {
      const int row = wm * 64 + fm * 16 + l15;
      const int idx = row * 4 + rsw;
      const f16x8 ahf = ((const f16x8*)Ah)[idx];
      const f16x8 alf = ((const f16x8*)Al)[idx];
#pragma unroll
      for (int fn = 0; fn < 4; ++fn) {
        acc[fm][fn] = __builtin_amdgcn_mfma_f32_16x16x32_f16(ahf, bhf[fn], acc[fm][fn], 0, 0, 0);
        acc[fm][fn] = __builtin_amdgcn_mfma_f32_16x16x32_f16(ahf, blf[fn], acc[fm][fn], 0, 0, 0);
        acc[fm][fn] = __builtin_amdgcn_mfma_f32_16x16x32_f16(alf, bhf[fn], acc[fm][fn], 0, 0, 0);
      }
    }
  }

  // epilogue: C/D frag layout col = lane&15, row = (lane>>4)*4 + reg
  if (m0 < NU * BK) {
#pragma unroll
    for (int fm = 0; fm < 4; ++fm) {
      const int u = (m0 >> 4) + wm * 4 + fm;
#pragma unroll
      for (int fn = 0; fn < 4; ++fn) {
        const f32x4 a = acc[fm][fn];
        float s = a.x * a.x + a.y * a.y + a.z * a.z + a.w * a.w;
        s += __shfl_xor(s, 16);
        s += __shfl_xor(s, 32);   // 16-row (one unit) column sum
        if (lk == 0)
          part[(size_t)u * NTOT + nq0 + wn * 64 + fn * 16 + l15] = s;
      }
    }
  } else {
#pragma unroll
    for (int fn = 0; fn < 4; ++fn) {
      float s = 0.f;
#pragma unroll
      for (int fm = 0; fm < 4; ++fm) {
        const f32x4 a = acc[fm][fn];
        s += a.x * a.x + a.y * a.y + a.z * a.z + a.w * a.w;
      }
      s += __shfl_xor(s, 16);
      s += __shfl_xor(s, 32);
      if (lk == 0) nred[wm][wn * 64 + fn * 16 + l15] = s;
    }
    __syncthreads();
    if (tid < 128)
      nupart[(size_t)((m0 - NU * BK) >> 7) * NTOT + nq0 + tid] =
          nred[0][tid] + nred[1][tid];
  }
}

// ---------------- update: score+argmax+coeffs+proj, rT hi/lo in-place -------
// e-chunked staging (2 x 256), LDS ~30 KB. rho kept in registers (rc0/rc1)
// for the proj phase -- each thread projects exactly the elements it loaded.
__launch_bounds__(256, 4)
__global__ void update2(const float* __restrict__ basis,
                        f16* __restrict__ rThi, f16* __restrict__ rTlo,
                        const float* __restrict__ part,
                        const float* __restrict__ nupart,
                        unsigned char* __restrict__ used,
                        float* __restrict__ init_energy,
                        const int depth) {
  __shared__ float bshc[CH * BSP];   // 17.4 KB  basis chunk [e_local][k], pad 17
  __shared__ float rsc[C_N * RSP];   // 8.4 KB   rho chunk   [c][e_local]
  __shared__ float prt[4][BK * C_N];
  __shared__ float coeffs[BK * C_N];
  __shared__ float epart[256];
  __shared__ float sval[NU];
  __shared__ float scale_sh[C_N];
  __shared__ int sbu;
  const int b = blockIdx.x;
  const int tid = threadIdx.x;
  const int c = tid >> 5, seg = tid & 31;
  const size_t row = ((size_t)b * C_N + c) * E_N;
  float rc0[8], rc1[8];   // this thread's rho elements, chunk0/chunk1

  if (tid < C_N) {
    float nu = 0.f;
#pragma unroll
    for (int t4 = 0; t4 < 4; ++t4)
      nu += nupart[(size_t)t4 * NTOT + b * C_N + tid];
    const float inv = 1.f / (sqrtf(nu) + EPSV);
    scale_sh[tid] = inv * inv;
  }
  __syncthreads();
  if (tid < NU) {   // score[u]; masked by used (scores >= 0 -> -1 sentinel)
    const float* pu = part + (size_t)tid * NTOT + b * C_N;
    float s = 0.f;
#pragma unroll
    for (int cc = 0; cc < C_N; ++cc) s = fmaf(pu[cc], scale_sh[cc], s);
    if (used[(size_t)b * NU + tid]) s = -1.f;
    sval[tid] = s;
  }
  // load chunk0 -> regs + rsc, energy part
  float en = 0.f;
  {
    const f16x8 h = *(const f16x8*)&rThi[row + seg * 8];
    const f16x8 l = *(const f16x8*)&rTlo[row + seg * 8];
#pragma unroll
    for (int j = 0; j < 8; ++j) {
      const float v = (float)h[j] + (float)l[j];
      rc0[j] = v; en = fmaf(v, v, en);
    }
    *(float4*)&rsc[c * RSP + seg * 8] = *(float4*)&rc0[0];
    *(float4*)&rsc[c * RSP + seg * 8 + 4] = *(float4*)&rc0[4];
  }
  __syncthreads();                 // sval + rsc chunk0 ready
  if (tid == 255) {                // first-max-wins argmax (jnp.argmax)
    float bs = -2.f; int bi = 0;
    for (int u = 0; u < NU; ++u)
      if (sval[u] > bs) { bs = sval[u]; bi = u; }
    sbu = bi;
  }
  __syncthreads();
  const int bu = sbu;
  const float* bp = basis + (size_t)bu * E_N * BK;
  for (int i = tid; i < CH * BK / 4; i += 256) {   // stage basis chunk0
    const float4 wv = ((const float4*)bp)[i];
    const int f0 = i * 4, e = f0 >> 4, k = f0 & 15;
    bshc[e * BSP + k] = wv.x;     bshc[e * BSP + k + 1] = wv.y;
    bshc[e * BSP + k + 2] = wv.z; bshc[e * BSP + k + 3] = wv.w;
  }
  __syncthreads();
  {  // coeffs partials chunk0: (k, c2, half) = 16 x 8 x 2
    const int k = tid >> 4, c2 = (tid >> 1) & 7, hh = tid & 1;
    float s = 0.f;
    const int e0 = hh * 128;
    for (int e = e0; e < e0 + 128; ++e)
      s = fmaf(bshc[e * BSP + k], rsc[c2 * RSP + e], s);
    prt[hh][k * C_N + c2] = s;
  }
  __syncthreads();                 // chunk0 consumed
  {  // load chunk1 -> regs + rsc, energy part
    const f16x8 h = *(const f16x8*)&rThi[row + CH + seg * 8];
    const f16x8 l = *(const f16x8*)&rTlo[row + CH + seg * 8];
#pragma unroll
    for (int j = 0; j < 8; ++j) {
      const float v = (float)h[j] + (float)l[j];
      rc1[j] = v; en = fmaf(v, v, en);
    }
    *(float4*)&rsc[c * RSP + seg * 8] = *(float4*)&rc1[0];
    *(float4*)&rsc[c * RSP + seg * 8 + 4] = *(float4*)&rc1[4];
  }
  for (int i = tid; i < CH * BK / 4; i += 256) {   // stage basis chunk1
    const float4 wv = ((const float4*)bp)[CH * BK / 4 + i];
    const int f0 = i * 4, e = f0 >> 4, k = f0 & 15;   // e local to chunk1
    bshc[e * BSP + k] = wv.x;     bshc[e * BSP + k + 1] = wv.y;
    bshc[e * BSP + k + 2] = wv.z; bshc[e * BSP + k + 3] = wv.w;
  }
  epart[tid] = en;
  __syncthreads();
  {  // coeffs partials chunk1
    const int k = tid >> 4, c2 = (tid >> 1) & 7, hh = tid & 1;
    float s = 0.f;
    const int e0 = hh * 128;
    for (int e = e0; e < e0 + 128; ++e)
      s = fmaf(bshc[e * BSP + k], rsc[c2 * RSP + e], s);
    prt[2 + hh][k * C_N + c2] = s;
  }
  __syncthreads();
  if (tid < 128)
    coeffs[tid] = (prt[0][tid] + prt[1][tid]) + (prt[2][tid] + prt[3][tid]);
  for (int s = 128; s > 0; s >>= 1) {   // deterministic energy tree
    if (tid < s) epart[tid] += epart[tid + s];
    __syncthreads();
  }
  const float etot = epart[0];
  float ie;
  if (depth == 0) {
    ie = etot;
    if (tid == 0) init_energy[b] = etot;
  } else {
    ie = init_energy[b];
  }
  const bool act = etot > THR * ie;   // block-uniform
  if (act) {
    // proj chunk1 (bshc holds chunk1; rho from rc1), coalesced f16 store
    {
      f16x8 oh, ol;
#pragma unroll
      for (int j = 0; j < 8; ++j) {
        const int e = seg * 8 + j;
        float pv = 0.f;
#pragma unroll
        for (int k = 0; k < BK; ++k)
          pv = fmaf(bshc[e * BSP + k], coeffs[k * C_N + c], pv);
        const float rv = rc1[j] - pv;
        const f16 h = (f16)rv;
        oh[j] = h; ol[j] = (f16)(rv - (float)h);
      }
      *(f16x8*)&rThi[row + CH + seg * 8] = oh;
      *(f16x8*)&rTlo[row + CH + seg * 8] = ol;
    }
    __syncthreads();   // all proj-chunk1 reads of bshc done before restage
    for (int i = tid; i < CH * BK / 4; i += 256) {   // restage basis chunk0
      const float4 wv = ((const float4*)bp)[i];
      const int f0 = i * 4, e = f0 >> 4, k = f0 & 15;
      bshc[e * BSP + k] = wv.x;     bshc[e * BSP + k + 1] = wv.y;
      bshc[e * BSP + k + 2] = wv.z; bshc[e * BSP + k + 3] = wv.w;
    }
    __syncthreads();
    {  // proj chunk0 (rho from rc0)
      f16x8 oh, ol;
#pragma unroll
      for (int j = 0; j < 8; ++j) {
        const int e = seg * 8 + j;
        float pv = 0.f;
#pragma unroll
        for (int k = 0; k < BK; ++k)
          pv = fmaf(bshc[e * BSP + k], coeffs[k * C_N + c], pv);
        const float rv = rc0[j] - pv;
        const f16 h = (f16)rv;
        oh[j] = h; ol[j] = (f16)(rv - (float)h);
      }
      *(f16x8*)&rThi[row + seg * 8] = oh;
      *(f16x8*)&rTlo[row + seg * 8] = ol;
    }
    if (tid == 0) used[(size_t)b * NU + bu] = 1;
  }
}

// ---------------- finalize: out[b][e][c] = x - (hi+lo)*RINV -----------------
__launch_bounds__(256)
__global__ void finalize2(const float* __restrict__ x,
                          const f16* __restrict__ rThi,
                          const f16* __restrict__ rTlo,
                          float* __restrict__ out) {
  __shared__ float TT[C_N * FSP];
  const int tid = threadIdx.x;
  const int b = blockIdx.x;
  const int c = tid >> 5, seg = tid & 31;
  const size_t row = ((size_t)b * C_N + c) * E_N;
#pragma unroll
  for (int hf = 0; hf < 2; ++hf) {
    const int e0 = seg * 16 + hf * 8;
    const f16x8 h = *(const f16x8*)&rThi[row + e0];
    const f16x8 l = *(const f16x8*)&rTlo[row + e0];
#pragma unroll
    for (int j = 0; j < 8; ++j)
      TT[c * FSP + e0 + j] = (float)h[j] + (float)l[j];
  }
  __syncthreads();
  const float* xb = x + (size_t)b * E_N * C_N;
  float* ob = out + (size_t)b * E_N * C_N;
  for (int i = tid; i < E_N * C_N / 4; i += 256) {
    const float4 xv = ((const float4*)xb)[i];
    const int e = i >> 1, c4 = (i & 1) * 4;
    float4 o;
    o.x = xv.x - TT[(c4 + 0) * FSP + e] * RINV;
    o.y = xv.y - TT[(c4 + 1) * FSP + e] * RINV;
    o.z = xv.z - TT[(c4 + 2) * FSP + e] * RINV;
    o.w = xv.w - TT[(c4 + 3) * FSP + e] * RINV;
    ((float4*)ob)[i] = o;
  }
}

extern "C" void kernel_launch(void* const* d_in, const int* in_sizes, int n_in,
                              void* d_out, int out_size, void* d_ws, size_t ws_size,
                              hipStream_t stream) {
  const float* x      = (const float*)d_in[0];
  const float* basis  = (const float*)d_in[1];
  const float* hasher = (const float*)d_in[2];
  float* out = (float*)d_out;

  // workspace layout (~75.8 MB)
  float* part        = (float*)d_ws;                         // 8 MB
  float* nupart      = part + (size_t)NU * NTOT;             // 512 KB
  float* init_energy = nupart + (size_t)4 * NTOT;            // 16 KB
  f16*   whi         = (f16*)(init_energy + B_N);            // 1.5 MB
  f16*   wlo         = whi + (size_t)MROWS * E_N;            // 1.5 MB
  f16*   rThi        = wlo + (size_t)MROWS * E_N;            // 32 MB
  f16*   rTlo        = rThi + (size_t)NTOT * E_N;            // 32 MB
  unsigned char* used = (unsigned char*)(rTlo + (size_t)NTOT * E_N); // 256 KB

  hipMemsetAsync(used, 0, (size_t)B_N * NU, stream);
  build_w<<<MROWS, 256, 0, stream>>>(basis, hasher, whi, wlo);
  init_convert<<<B_N, 256, 0, stream>>>(x, rThi, rTlo);

  for (int d = 0; d < NDEPTH; ++d) {
    mfma_score<<<3072, 256, 0, stream>>>(whi, wlo, rThi, rTlo, part, nupart);
    update2<<<B_N, 256, 0, stream>>>(basis, rThi, rTlo, part, nupart, used,
                                     init_energy, d);
  }
  finalize2<<<B_N, 256, 0, stream>>>(x, rThi, rTlo, out);
}